// Round 18
// baseline (152.706 us; speedup 1.0000x reference)
//
#include <hip/hip_runtime.h>
#include <hip/hip_bf16.h>
#include <stdint.h>

#define B_   64
#define N_   128
#define H_   256
#define FH   1024   // 4*H
#define NT   32     // trunks
#define TL   32     // trunk len
#define LV   3
#define OUT_ 10
#define NTRK 96     // level x trunk instances
#define UNITS 384   // NTRK x 4 batch-quarters (M=16 each)
#define NWORK 256   // worker blocks (1 per CU)
#define WST  272    // LDS weight row stride (256 + 16 pad: conflict-free b128)

typedef __attribute__((ext_vector_type(4))) int   int4v;
typedef __attribute__((ext_vector_type(4))) float f32x4;

#define QW  (0.0625f / 127.0f)         // weight quant scale
#define QH  (1.0f / 127.0f)            // h quant scale
#define QS  (QW * QH)                  // combined dequant for i32 acc
#define L2E 1.442695041f               // log2(e)
#define QSI (-L2E * QS)                // sigmoid-gate dequant (pre-negated+scaled)
#define QSG (2.0f * L2E * QS)          // tanh-gate dequant
#define C2  (2.0f * L2E)               // tanh(c) input scale

__device__ inline float exp2f_(float x) { return __builtin_amdgcn_exp2f(x); }
__device__ inline float rcpf_(float x)  { return __builtin_amdgcn_rcpf(x); }

// merged prep. blocks 0..767: u/v. blocks 768..1535: W_hh->int8 + out init.
// block 1536: LPT sort (rank trunks by len desc) + queue counter reset.
__global__ void prep_all(const float* __restrict__ W_enc, const float* __restrict__ b_enc,
                         const float* __restrict__ W_ih, const float* __restrict__ b_ih,
                         const float* __restrict__ b_hh, const float* __restrict__ W_hh,
                         const float* __restrict__ b_lin, const int* __restrict__ trunk_len,
                         float* __restrict__ u, float* __restrict__ v,
                         char* __restrict__ whh_i8, float* __restrict__ out,
                         int* __restrict__ sorted, int* __restrict__ counter) {
    int blk = blockIdx.x;
    int tid = threadIdx.x;
    if (blk < 768) {
        int j = blk * 4 + (tid >> 6);   // 0..3071
        int lane = tid & 63;
        const float4 w  = ((const float4*)(W_ih + (size_t)j * H_))[lane];
        const float4 we = ((const float4*)W_enc)[lane];
        const float4 be = ((const float4*)b_enc)[lane];
        float du = w.x * we.x + w.y * we.y + w.z * we.z + w.w * we.w;
        float dv = w.x * be.x + w.y * be.y + w.z * be.z + w.w * be.w;
        for (int m = 32; m >= 1; m >>= 1) { du += __shfl_xor(du, m); dv += __shfl_xor(dv, m); }
        if (lane == 0) {
            int g = (j & 1023) >> 8;
            float s = (g == 2) ? (2.0f * L2E) : (-L2E);
            u[j] = s * du;
            v[j] = s * (dv + b_ih[j] + b_hh[j]);
        }
    } else if (blk < 1536) {
        int gid = (blk - 768) * 256 + tid;   // 0..196607, each converts 4
        const float4 w = ((const float4*)W_hh)[gid];
        char4 o;
        int a0 = __float2int_rn(w.x * (127.0f / 0.0625f));
        int a1 = __float2int_rn(w.y * (127.0f / 0.0625f));
        int a2 = __float2int_rn(w.z * (127.0f / 0.0625f));
        int a3 = __float2int_rn(w.w * (127.0f / 0.0625f));
        a0 = a0 > 127 ? 127 : (a0 < -127 ? -127 : a0);
        a1 = a1 > 127 ? 127 : (a1 < -127 ? -127 : a1);
        a2 = a2 > 127 ? 127 : (a2 < -127 ? -127 : a2);
        a3 = a3 > 127 ? 127 : (a3 < -127 ? -127 : a3);
        o.x = (char)a0; o.y = (char)a1; o.z = (char)a2; o.w = (char)a3;
        ((char4*)whh_i8)[gid] = o;
        if (gid < B_ * OUT_) {
            int oo = gid % OUT_;
            out[gid] = b_lin[oo] + b_lin[OUT_ + oo] + b_lin[2 * OUT_ + oo];
        }
    } else {
        // LPT order: sorted[rank] = trunk id, rank 0 = longest
        if (tid < NTRK) {
            int li = trunk_len[tid]; if (li < 1) li = 1;
            int rank = 0;
            for (int j2 = 0; j2 < NTRK; ++j2) {
                int lj = trunk_len[j2]; if (lj < 1) lj = 1;
                rank += (lj > li) || (lj == li && j2 < tid);
            }
            sorted[rank] = tid;
        }
        if (tid == 0) *counter = 0;
    }
}

// Persistent work-queue LSTM (R14 structure: 256 workers x 1024 thr, 4 w/EU,
// unit = trunk x batch-quarter, M=16, LPT-claimed). NEW: the kernel is per-CU
// L2-BW bound (R14: 256 KB W_hh stream / 2.36us step = 108 GB/s ~= 80% of the
// per-CU L2 share). Gates i,f (512 rows, 128 KB) are staged in LDS ONCE per
// unit claim; only gates g,o stream from L2 per step -> per-step L2 traffic
// halves. LDS weight rows use stride 272 B: b128 reads hit each bank exactly
// 8x/wave (the 1KB minimum) - no excess conflicts.
__global__ __launch_bounds__(1024) __attribute__((amdgpu_waves_per_eu(4, 4)))
void lstm_main(const float* __restrict__ bfeat, const int* __restrict__ trunk_idx,
               const int* __restrict__ trunk_len,
               const char* __restrict__ whh_i8,
               const float* __restrict__ u, const float* __restrict__ v,
               const float* __restrict__ W_lin, const int* __restrict__ sorted,
               int* __restrict__ counter, float* __restrict__ out) {
    __shared__ __align__(16) char wbuf[512][WST];     // gates i,f weights: 139,264 B
    __shared__ __align__(16) char hbuf[2][16][272];   // int8 h, parity dbuf
    __shared__ __align__(16) float sbuf[2][16];       // batch scalars, parity dbuf
    __shared__ int sh_uid;

    const int tid = threadIdx.x;
    const int w = tid >> 6;              // wave 0..15 -> gate-col slice w*16..w*16+15 per gate
    const int lane = tid & 63;
    const int col = lane & 15;
    const int q = lane >> 4;

    // loop-invariant zero C for MFMA chain heads
    int4v z4; z4[0] = 0; z4[1] = 0; z4[2] = 0; z4[3] = 0;
    asm volatile("" : "+v"(z4));

    for (;;) {
        if (tid == 0) sh_uid = atomicAdd(counter, 1);
        __syncthreads();                 // claim visible; orders prev epilogue + wbuf reuse
        const int uid = sh_uid;
        if (uid >= UNITS) break;

        const int r = uid >> 2, qq = uid & 3;
        const int tt = sorted[r];
        const int l = tt >> 5;
        const int b0 = qq * 16;

        int len = trunk_len[tt];
        if (len < 1) len = 1;
        const int* tix = trunk_idx + tt * TL;
        const char* whh_l = whh_i8 + (size_t)l * FH * H_;

        // ---- stage gates i,f (rows 0..511) into LDS: 128 B per thread ----
        {
            int row = tid >> 1, half = tid & 1;
            const int4v* s = (const int4v*)(whh_l + (size_t)row * H_ + half * 128);
            int4v* d = (int4v*)(&wbuf[row][half * 128]);
            #pragma unroll
            for (int i = 0; i < 8; ++i) d[i] = s[i];
        }

        float u_r[4], v_r[4];
        {
            const float* u_l = u + l * FH;
            const float* v_l = v + l * FH;
            #pragma unroll
            for (int g = 0; g < 4; ++g) {
                int j = g * 256 + w * 16 + col;
                u_r[g] = u_l[j];
                v_r[g] = v_l[j];
            }
        }

        float c_r[4];                    // [rg]

        if (tid < 16) sbuf[0][tid] = bfeat[(b0 + tid) * N_ + tix[0]];
        __syncthreads();                 // wbuf + sbuf[0] ready

        // ---- peeled step 0: c0 = 0 ----
        {
            if (len > 1 && tid < 16) sbuf[1][tid] = bfeat[(b0 + tid) * N_ + tix[1]];
            f32x4 sv = *(const f32x4*)&sbuf[0][q * 4];
            #pragma unroll
            for (int rg = 0; rg < 4; ++rg) {
                float xi = fmaf(sv[rg], u_r[0], v_r[0]);
                float xg = fmaf(sv[rg], u_r[2], v_r[2]);
                float xo = fmaf(sv[rg], u_r[3], v_r[3]);
                float si = rcpf_(exp2f_(xi) + 1.0f);
                float so = rcpf_(exp2f_(xo) + 1.0f);
                float tg = fmaf(-2.0f, rcpf_(exp2f_(xg) + 1.0f), 1.0f);
                float cn = si * tg;
                c_r[rg] = cn;
                float th127 = fmaf(-254.0f, rcpf_(exp2f_(C2 * cn) + 1.0f), 127.0f);
                hbuf[1][q * 4 + rg][w * 16 + col] = (char)__float2int_rn(so * th127);
            }
            __syncthreads();
        }

        for (int p = 1; p < len; ++p) {
            const int ri = p & 1, wi = ri ^ 1;

            if (p + 1 < len && tid < 16)
                sbuf[wi][tid] = bfeat[(b0 + tid) * N_ + tix[p + 1]];

            // streamed B-fragments for gates g,o (the remaining 128 KB/step of L2)
            int4v Bs[2][4];
            #pragma unroll
            for (int gg = 0; gg < 2; ++gg) {
                int j = (2 + gg) * 256 + w * 16 + col;
                const char* bp = whh_l + (size_t)j * H_ + q * 16;
                #pragma unroll
                for (int k = 0; k < 4; ++k)
                    Bs[gg][k] = *(const int4v*)(bp + k * 64);
            }

            int4v a_f[4];
            #pragma unroll
            for (int k = 0; k < 4; ++k)
                a_f[k] = *(const int4v*)&hbuf[ri][col][k * 64 + q * 16];

            f32x4 sv = *(const f32x4*)&sbuf[ri][q * 4];

            int4v acc[4];
            // gates i,f from LDS
            #pragma unroll
            for (int g = 0; g < 2; ++g) {
                const char* wp = &wbuf[g * 256 + w * 16 + col][q * 16];
                int4v b0f = *(const int4v*)(wp);
                acc[g] = __builtin_amdgcn_mfma_i32_16x16x64_i8(a_f[0], b0f, z4, 0, 0, 0);
                #pragma unroll
                for (int k = 1; k < 4; ++k) {
                    int4v bkf = *(const int4v*)(wp + k * 64);
                    acc[g] = __builtin_amdgcn_mfma_i32_16x16x64_i8(a_f[k], bkf, acc[g], 0, 0, 0);
                }
            }
            // gates g,o from the streamed fragments
            #pragma unroll
            for (int gg = 0; gg < 2; ++gg) {
                acc[2 + gg] = __builtin_amdgcn_mfma_i32_16x16x64_i8(a_f[0], Bs[gg][0], z4, 0, 0, 0);
                #pragma unroll
                for (int k = 1; k < 4; ++k)
                    acc[2 + gg] = __builtin_amdgcn_mfma_i32_16x16x64_i8(a_f[k], Bs[gg][k], acc[2 + gg], 0, 0, 0);
            }

            #pragma unroll
            for (int rg = 0; rg < 4; ++rg) {
                float xi = fmaf((float)acc[0][rg], QSI, fmaf(sv[rg], u_r[0], v_r[0]));
                float xf = fmaf((float)acc[1][rg], QSI, fmaf(sv[rg], u_r[1], v_r[1]));
                float xg = fmaf((float)acc[2][rg], QSG, fmaf(sv[rg], u_r[2], v_r[2]));
                float xo = fmaf((float)acc[3][rg], QSI, fmaf(sv[rg], u_r[3], v_r[3]));
                float si = rcpf_(exp2f_(xi) + 1.0f);          // sigmoid
                float sf = rcpf_(exp2f_(xf) + 1.0f);
                float so = rcpf_(exp2f_(xo) + 1.0f);
                float tg = fmaf(-2.0f, rcpf_(exp2f_(xg) + 1.0f), 1.0f);   // tanh
                float cn = fmaf(sf, c_r[rg], si * tg);
                c_r[rg] = cn;
                float th127 = fmaf(-254.0f, rcpf_(exp2f_(C2 * cn) + 1.0f), 127.0f);
                hbuf[wi][q * 4 + rg][w * 16 + col] = (char)__float2int_rn(so * th127);
            }

            __syncthreads();   // single barrier: new h (wi) + next sbuf ready
        }

        // epilogue: h_last in hbuf[len & 1]; bias pre-initialized by prep
        const char (*hl)[272] = hbuf[len & 1];
        const float* wl = W_lin + l * H_ * OUT_;
        if (tid < 16 * OUT_) {
            int m = tid / OUT_, o = tid % OUT_;
            float s = 0.f;
            for (int k = 0; k < H_; ++k)
                s += (float)hl[m][k] * QH * wl[k * OUT_ + o];
            atomicAdd(&out[(b0 + m) * OUT_ + o], s);
        }
        // next iteration's claim barrier orders these reads before hbuf/wbuf reuse
    }
}

extern "C" void kernel_launch(void* const* d_in, const int* in_sizes, int n_in,
                              void* d_out, int out_size, void* d_ws, size_t ws_size,
                              hipStream_t stream) {
    const float* bfeat = (const float*)d_in[0];
    const int*   tidx  = (const int*)d_in[1];
    const int*   tlen  = (const int*)d_in[2];
    const float* W_enc = (const float*)d_in[3];
    const float* b_enc = (const float*)d_in[4];
    const float* W_ih  = (const float*)d_in[5];
    const float* W_hh  = (const float*)d_in[6];
    const float* b_ih  = (const float*)d_in[7];
    const float* b_hh  = (const float*)d_in[8];
    const float* W_lin = (const float*)d_in[9];
    const float* b_lin = (const float*)d_in[10];
    float* out = (float*)d_out;

    char*  whh_i8 = (char*)d_ws;                               // 786,432 B
    float* u = (float*)((char*)d_ws + 786432);                 // 12,288 B
    float* v = (float*)((char*)d_ws + 786432 + 12288);         // 12,288 B
    int* sorted  = (int*)((char*)d_ws + 811008);               // 384 B
    int* counter = (int*)((char*)d_ws + 811392);               // 4 B

    prep_all<<<1537, 256, 0, stream>>>(W_enc, b_enc, W_ih, b_ih, b_hh, W_hh, b_lin,
                                       tlen, u, v, whh_i8, out, sorted, counter);
    lstm_main<<<NWORK, 1024, 0, stream>>>(bfeat, tidx, tlen, whh_i8, u, v, W_lin,
                                          sorted, counter, out);
}

// Round 19
// 146.354 us; speedup vs baseline: 1.0434x; 1.0434x over previous
//
#include <hip/hip_runtime.h>
#include <hip/hip_bf16.h>
#include <stdint.h>

#define B_   64
#define N_   128
#define H_   256
#define FH   1024   // 4*H
#define NT   32     // trunks
#define TL   32     // trunk len
#define LV   3
#define OUT_ 10
#define NTRK 96     // level x trunk instances
#define UNITS 384   // NTRK x 4 batch-quarters (M=16 each)

typedef __attribute__((ext_vector_type(4))) int   int4v;
typedef __attribute__((ext_vector_type(4))) float f32x4;

#define QW  (0.0625f / 127.0f)         // weight quant scale
#define QH  (1.0f / 127.0f)            // h quant scale
#define QS  (QW * QH)                  // combined dequant for i32 acc
#define L2E 1.442695041f               // log2(e)
#define QSI (-L2E * QS)                // sigmoid-gate dequant (pre-negated+scaled)
#define QSG (2.0f * L2E * QS)          // tanh-gate dequant
#define C2  (2.0f * L2E)               // tanh(c) input scale

__device__ inline float exp2f_(float x) { return __builtin_amdgcn_exp2f(x); }
__device__ inline float rcpf_(float x)  { return __builtin_amdgcn_rcpf(x); }

// merged prep. blocks 0..767: u/v. blocks 768..1535: W_hh->int8 + out init.
// block 1536: LPT sort (rank trunks by len desc) + work-queue counter reset.
__global__ void prep_all(const float* __restrict__ W_enc, const float* __restrict__ b_enc,
                         const float* __restrict__ W_ih, const float* __restrict__ b_ih,
                         const float* __restrict__ b_hh, const float* __restrict__ W_hh,
                         const float* __restrict__ b_lin, const int* __restrict__ trunk_len,
                         float* __restrict__ u, float* __restrict__ v,
                         char* __restrict__ whh_i8, float* __restrict__ out,
                         int* __restrict__ sorted, int* __restrict__ counter) {
    int blk = blockIdx.x;
    int tid = threadIdx.x;
    if (blk < 768) {
        int j = blk * 4 + (tid >> 6);   // 0..3071
        int lane = tid & 63;
        const float4 w  = ((const float4*)(W_ih + (size_t)j * H_))[lane];
        const float4 we = ((const float4*)W_enc)[lane];
        const float4 be = ((const float4*)b_enc)[lane];
        float du = w.x * we.x + w.y * we.y + w.z * we.z + w.w * we.w;
        float dv = w.x * be.x + w.y * be.y + w.z * be.z + w.w * be.w;
        for (int m = 32; m >= 1; m >>= 1) { du += __shfl_xor(du, m); dv += __shfl_xor(dv, m); }
        if (lane == 0) {
            int g = (j & 1023) >> 8;
            float s = (g == 2) ? (2.0f * L2E) : (-L2E);
            u[j] = s * du;
            v[j] = s * (dv + b_ih[j] + b_hh[j]);
        }
    } else if (blk < 1536) {
        int gid = (blk - 768) * 256 + tid;   // 0..196607, each converts 4
        const float4 w = ((const float4*)W_hh)[gid];
        char4 o;
        int a0 = __float2int_rn(w.x * (127.0f / 0.0625f));
        int a1 = __float2int_rn(w.y * (127.0f / 0.0625f));
        int a2 = __float2int_rn(w.z * (127.0f / 0.0625f));
        int a3 = __float2int_rn(w.w * (127.0f / 0.0625f));
        a0 = a0 > 127 ? 127 : (a0 < -127 ? -127 : a0);
        a1 = a1 > 127 ? 127 : (a1 < -127 ? -127 : a1);
        a2 = a2 > 127 ? 127 : (a2 < -127 ? -127 : a2);
        a3 = a3 > 127 ? 127 : (a3 < -127 ? -127 : a3);
        o.x = (char)a0; o.y = (char)a1; o.z = (char)a2; o.w = (char)a3;
        ((char4*)whh_i8)[gid] = o;
        if (gid < B_ * OUT_) {
            int oo = gid % OUT_;
            out[gid] = b_lin[oo] + b_lin[OUT_ + oo] + b_lin[2 * OUT_ + oo];
        }
    } else {
        // LPT order: sorted[rank] = trunk id, rank 0 = longest
        if (tid < NTRK) {
            int li = trunk_len[tid]; if (li < 1) li = 1;
            int rank = 0;
            for (int j2 = 0; j2 < NTRK; ++j2) {
                int lj = trunk_len[j2]; if (lj < 1) lj = 1;
                rank += (lj > li) || (lj == li && j2 < tid);
            }
            sorted[rank] = tid;
        }
        if (tid == 0) *counter = 0;
    }
}

// Persistent work-queue LSTM (best measured config, R14: 146.6 us total).
// 256 worker blocks (1/CU), 1024 threads = 16 waves = 4 waves/EU. Unit =
// (trunk instance, batch-quarter): M=16 rows, all 1024 gate cols, K=256,
// run to completion by one block; units claimed LPT-sorted (longest first)
// via global atomic counter, so makespan ~ pole-unit latency.
// STRUCTURAL CEILING (R15-R18 ablations): step time = ~0.97us fixed
// (barrier + dependency chains; survives L2->LDS staging, weight residency,
// instruction dieting) + transcendental issue (10 trans/cell, irreducible).
// Co-residency (more blocks/CU) infeasible: body needs >=64 VGPR, so
// >4 waves/EU spills (R15/R16). Weight streaming from L2 proven cost-free.
__global__ __launch_bounds__(1024) __attribute__((amdgpu_waves_per_eu(4, 4)))
void lstm_main(const float* __restrict__ bfeat, const int* __restrict__ trunk_idx,
               const int* __restrict__ trunk_len,
               const char* __restrict__ whh_i8,
               const float* __restrict__ u, const float* __restrict__ v,
               const float* __restrict__ W_lin, const int* __restrict__ sorted,
               int* __restrict__ counter, float* __restrict__ out) {
    __shared__ __align__(16) char hbuf[2][16][272];   // int8 h, parity dbuf, 256+16 pad
    __shared__ __align__(16) float sbuf[2][16];       // batch scalars, parity dbuf
    __shared__ int sh_uid;

    const int tid = threadIdx.x;
    const int w = tid >> 6;              // wave 0..15 -> gate-col slice w*16..w*16+15 per gate
    const int lane = tid & 63;
    const int col = lane & 15;
    const int q = lane >> 4;

    // loop-invariant zero C for MFMA chain heads
    int4v z4; z4[0] = 0; z4[1] = 0; z4[2] = 0; z4[3] = 0;
    asm volatile("" : "+v"(z4));

    for (;;) {
        if (tid == 0) sh_uid = atomicAdd(counter, 1);
        __syncthreads();                 // claim visible; orders prev epilogue reads too
        const int uid = sh_uid;
        if (uid >= UNITS) break;

        const int r = uid >> 2, qq = uid & 3;
        const int tt = sorted[r];
        const int l = tt >> 5;
        const int b0 = qq * 16;

        int len = trunk_len[tt];
        if (len < 1) len = 1;
        const int* tix = trunk_idx + tt * TL;
        const char* whh_l = whh_i8 + (size_t)l * FH * H_;

        // W_hh fragments: wave w owns gate cols j = g*256 + w*16 + col.
        // (Compiler streams these from L2 per step — measured cost-free.)
        int4v Breg[4][4];
        #pragma unroll
        for (int g = 0; g < 4; ++g) {
            int j = g * 256 + w * 16 + col;
            const char* bp = whh_l + (size_t)j * H_ + q * 16;
            #pragma unroll
            for (int k = 0; k < 4; ++k)
                Breg[g][k] = *(const int4v*)(bp + k * 64);
        }

        float u_r[4], v_r[4];
        {
            const float* u_l = u + l * FH;
            const float* v_l = v + l * FH;
            #pragma unroll
            for (int g = 0; g < 4; ++g) {
                int j = g * 256 + w * 16 + col;
                u_r[g] = u_l[j];
                v_r[g] = v_l[j];
            }
        }

        float c_r[4];                    // [rg]

        if (tid < 16) sbuf[0][tid] = bfeat[(b0 + tid) * N_ + tix[0]];
        __syncthreads();

        // ---- peeled step 0: c0 = 0 ----
        {
            if (len > 1 && tid < 16) sbuf[1][tid] = bfeat[(b0 + tid) * N_ + tix[1]];
            f32x4 sv = *(const f32x4*)&sbuf[0][q * 4];
            #pragma unroll
            for (int rg = 0; rg < 4; ++rg) {
                float xi = fmaf(sv[rg], u_r[0], v_r[0]);
                float xg = fmaf(sv[rg], u_r[2], v_r[2]);
                float xo = fmaf(sv[rg], u_r[3], v_r[3]);
                float si = rcpf_(exp2f_(xi) + 1.0f);
                float so = rcpf_(exp2f_(xo) + 1.0f);
                float tg = fmaf(-2.0f, rcpf_(exp2f_(xg) + 1.0f), 1.0f);
                float cn = si * tg;
                c_r[rg] = cn;
                float th127 = fmaf(-254.0f, rcpf_(exp2f_(C2 * cn) + 1.0f), 127.0f);
                hbuf[1][q * 4 + rg][w * 16 + col] = (char)__float2int_rn(so * th127);
            }
            __syncthreads();
        }

        for (int p = 1; p < len; ++p) {
            const int ri = p & 1, wi = ri ^ 1;

            if (p + 1 < len && tid < 16)
                sbuf[wi][tid] = bfeat[(b0 + tid) * N_ + tix[p + 1]];

            int4v a_f[4];
            #pragma unroll
            for (int k = 0; k < 4; ++k)
                a_f[k] = *(const int4v*)&hbuf[ri][col][k * 64 + q * 16];

            f32x4 sv = *(const f32x4*)&sbuf[ri][q * 4];

            int4v acc[4];
            #pragma unroll
            for (int g = 0; g < 4; ++g) {
                acc[g] = __builtin_amdgcn_mfma_i32_16x16x64_i8(a_f[0], Breg[g][0], z4, 0, 0, 0);
                #pragma unroll
                for (int k = 1; k < 4; ++k)
                    acc[g] = __builtin_amdgcn_mfma_i32_16x16x64_i8(a_f[k], Breg[g][k], acc[g], 0, 0, 0);
            }

            #pragma unroll
            for (int rg = 0; rg < 4; ++rg) {
                float xi = fmaf((float)acc[0][rg], QSI, fmaf(sv[rg], u_r[0], v_r[0]));
                float xf = fmaf((float)acc[1][rg], QSI, fmaf(sv[rg], u_r[1], v_r[1]));
                float xg = fmaf((float)acc[2][rg], QSG, fmaf(sv[rg], u_r[2], v_r[2]));
                float xo = fmaf((float)acc[3][rg], QSI, fmaf(sv[rg], u_r[3], v_r[3]));
                float si = rcpf_(exp2f_(xi) + 1.0f);          // sigmoid
                float sf = rcpf_(exp2f_(xf) + 1.0f);
                float so = rcpf_(exp2f_(xo) + 1.0f);
                float tg = fmaf(-2.0f, rcpf_(exp2f_(xg) + 1.0f), 1.0f);   // tanh
                float cn = fmaf(sf, c_r[rg], si * tg);
                c_r[rg] = cn;
                float th127 = fmaf(-254.0f, rcpf_(exp2f_(C2 * cn) + 1.0f), 127.0f);
                hbuf[wi][q * 4 + rg][w * 16 + col] = (char)__float2int_rn(so * th127);
            }

            __syncthreads();   // single barrier: new h (wi) + next sbuf ready
        }

        // epilogue: h_last in hbuf[len & 1]; bias pre-initialized by prep
        const char (*hl)[272] = hbuf[len & 1];
        const float* wl = W_lin + l * H_ * OUT_;
        if (tid < 16 * OUT_) {
            int m = tid / OUT_, o = tid % OUT_;
            float s = 0.f;
            for (int k = 0; k < H_; ++k)
                s += (float)hl[m][k] * QH * wl[k * OUT_ + o];
            atomicAdd(&out[(b0 + m) * OUT_ + o], s);
        }
        // next iteration's claim barrier orders these reads before hbuf reuse
    }
}

extern "C" void kernel_launch(void* const* d_in, const int* in_sizes, int n_in,
                              void* d_out, int out_size, void* d_ws, size_t ws_size,
                              hipStream_t stream) {
    const float* bfeat = (const float*)d_in[0];
    const int*   tidx  = (const int*)d_in[1];
    const int*   tlen  = (const int*)d_in[2];
    const float* W_enc = (const float*)d_in[3];
    const float* b_enc = (const float*)d_in[4];
    const float* W_ih  = (const float*)d_in[5];
    const float* W_hh  = (const float*)d_in[6];
    const float* b_ih  = (const float*)d_in[7];
    const float* b_hh  = (const float*)d_in[8];
    const float* W_lin = (const float*)d_in[9];
    const float* b_lin = (const float*)d_in[10];
    float* out = (float*)d_out;

    char*  whh_i8 = (char*)d_ws;                               // 786,432 B
    float* u = (float*)((char*)d_ws + 786432);                 // 12,288 B
    float* v = (float*)((char*)d_ws + 786432 + 12288);         // 12,288 B
    int* sorted  = (int*)((char*)d_ws + 811008);               // 384 B
    int* counter = (int*)((char*)d_ws + 811392);               // 4 B

    prep_all<<<1537, 256, 0, stream>>>(W_enc, b_enc, W_ih, b_ih, b_hh, W_hh, b_lin,
                                       tlen, u, v, whh_i8, out, sorted, counter);
    lstm_main<<<256, 1024, 0, stream>>>(bfeat, tidx, tlen, whh_i8, u, v, W_lin,
                                        sorted, counter, out);
}